// Round 1
// 1430.922 us; speedup vs baseline: 1.6788x; 1.6788x over previous
//
#include <hip/hip_runtime.h>
#include <hip/hip_bf16.h>
#include <stdint.h>

#define MDIM 4096
#define KDIM 4096
#define NDIM 11008

typedef __bf16 bf16x8 __attribute__((ext_vector_type(8)));
typedef float  f32x4  __attribute__((ext_vector_type(4)));

// 128x128 tile, BK=32, 256 threads = 4 waves in 2x2; each wave owns 64x64
// via 4x4 mfma_f32_16x16x32_bf16 fragments (16 MFMA per wave per k-step).
// LDS is bf16: A staged as [m][k] (linear, read-conflict-free), B dequantized
// at staging into transposed [n][k] with 16B-chunk XOR swizzle so both the
// b128 writes and reads are bank-uniform. Fragment contracts identical to the
// harness-verified round-3 kernel:
//   A operand: lane(fr,fq) holds A[m=16i+fr][k=fq*8+e]
//   B operand: lane(fr,fq) holds B[k=fq*8+e][n=16j+fr]
//   C/D:       col = lane&15, row = (lane>>4)*4 + r
__global__ __launch_bounds__(256) void int4_gemm_mfma(
    const float* __restrict__ A, const int* __restrict__ Q,
    const float* __restrict__ S, const int* __restrict__ Z,
    const float* __restrict__ bias, float* __restrict__ out)
{
    __shared__ __bf16 sA[128][32];   // [m][k] bf16, 8 KB, linear
    __shared__ __bf16 sB[128][32];   // [n][k] bf16, 8 KB, chunk-XOR swizzled

    // ---- XCD-chunked swizzle, bm fastest: each XCD walks one bn (Q) strip ----
    const int nbm = MDIM / 128;                      // 32
    const int nwg = (MDIM / 128) * (NDIM / 128);     // 2752 (divisible by 8)
    const int xcd = blockIdx.x & 7;
    const int wg  = xcd * (nwg >> 3) + (blockIdx.x >> 3);
    const int bm  = wg % nbm;
    const int bn  = wg / nbm;
    const int m0 = bm * 128, n0 = bn * 128;

    const int t    = threadIdx.x;
    const int lane = t & 63;
    const int wave = t >> 6;
    const int wm   = (wave >> 1) * 64;   // wave quadrant (64x64)
    const int wn   = (wave & 1) * 64;
    const int fr   = lane & 15;
    const int fq   = lane >> 4;          // k-octet

    // ---- staging maps ----
    // A: thread covers rows {t>>2, t>>2+64}, 8 consecutive k at (t&3)*8
    const int arow = t >> 2;             // 0..63
    const int acol = (t & 3) * 8;        // 0,8,16,24
    // B: thread covers n = {2*lane, 2*lane+1}, k-octet = wave (8 k rows)
    const int bn2    = lane * 2;         // 0..126
    const int bko    = wave * 8;         // k rows bko..bko+7
    const int bchunk = (wave ^ (lane & 3)) * 8;   // swizzled chunk, same for both n

    f32x4 acc[4][4];
    #pragma unroll
    for (int i = 0; i < 4; ++i)
        #pragma unroll
        for (int j = 0; j < 4; ++j)
            #pragma unroll
            for (int r = 0; r < 4; ++r)
                acc[i][j][r] = 0.0f;

    // B fragment read chunk (swizzle inverse): ((n>>1)&3) == ((fr>>1)&3)
    const int rch = (fq ^ ((fr >> 1) & 3)) * 8;

    for (int g = 0; g < KDIM / 128; ++g) {          // 32 groups, 4 k-steps each
        // group-wise dequant params for this thread's two n columns
        const float2 sc = *(const float2*)(S + (size_t)g * NDIM + n0 + bn2);
        const int2   zp = *(const int2*)  (Z + (size_t)g * NDIM + n0 + bn2);
        const float zs0 = -(float)zp.x * sc.x;
        const float zs1 = -(float)zp.y * sc.y;

        #pragma unroll
        for (int t4 = 0; t4 < 4; ++t4) {
            const int k0 = g * 128 + t4 * 32;

            __syncthreads();

            // ---- stage A: 128x32 fp32 -> bf16 LDS ----
            {
                const float* ap = A + (size_t)(m0 + arow) * KDIM + k0 + acol;
                float4 u0 = ((const float4*)ap)[0];
                float4 u1 = ((const float4*)ap)[1];
                const float* aq = ap + (size_t)64 * KDIM;
                float4 u2 = ((const float4*)aq)[0];
                float4 u3 = ((const float4*)aq)[1];
                bf16x8 v0, v1;
                v0[0] = (__bf16)u0.x; v0[1] = (__bf16)u0.y;
                v0[2] = (__bf16)u0.z; v0[3] = (__bf16)u0.w;
                v0[4] = (__bf16)u1.x; v0[5] = (__bf16)u1.y;
                v0[6] = (__bf16)u1.z; v0[7] = (__bf16)u1.w;
                v1[0] = (__bf16)u2.x; v1[1] = (__bf16)u2.y;
                v1[2] = (__bf16)u2.z; v1[3] = (__bf16)u2.w;
                v1[4] = (__bf16)u3.x; v1[5] = (__bf16)u3.y;
                v1[6] = (__bf16)u3.z; v1[7] = (__bf16)u3.w;
                *(bf16x8*)&sA[arow][acol]      = v0;
                *(bf16x8*)&sA[arow + 64][acol] = v1;
            }

            // ---- stage B: dequant 32x128 int4 -> bf16, transposed [n][k] ----
            {
                bf16x8 w0, w1;
                #pragma unroll
                for (int j = 0; j < 8; ++j) {
                    int2 q = *(const int2*)(Q + (size_t)(k0 + bko + j) * NDIM + n0 + bn2);
                    w0[j] = (__bf16)((float)q.x * sc.x + zs0);
                    w1[j] = (__bf16)((float)q.y * sc.y + zs1);
                }
                *(bf16x8*)&sB[bn2][bchunk]     = w0;
                *(bf16x8*)&sB[bn2 + 1][bchunk] = w1;
            }

            __syncthreads();

            // ---- fragments: single ds_read_b128 each ----
            bf16x8 aF[4], bF[4];
            #pragma unroll
            for (int i = 0; i < 4; ++i)
                aF[i] = *(const bf16x8*)&sA[wm + 16 * i + fr][fq * 8];
            #pragma unroll
            for (int j = 0; j < 4; ++j)
                bF[j] = *(const bf16x8*)&sB[wn + 16 * j + fr][rch];

            #pragma unroll
            for (int i = 0; i < 4; ++i)
                #pragma unroll
                for (int j = 0; j < 4; ++j)
                    acc[i][j] = __builtin_amdgcn_mfma_f32_16x16x32_bf16(
                                    aF[i], bF[j], acc[i][j], 0, 0, 0);
        }
    }

    // ---- epilogue: C/D col = lane&15, row = (lane>>4)*4 + r ----
    float bj[4];
    #pragma unroll
    for (int j = 0; j < 4; ++j)
        bj[j] = bias[n0 + wn + 16 * j + fr];

    #pragma unroll
    for (int i = 0; i < 4; ++i) {
        #pragma unroll
        for (int r = 0; r < 4; ++r) {
            const int m = m0 + wm + 16 * i + fq * 4 + r;
            float* op = out + (size_t)m * NDIM + n0 + wn + fr;
            #pragma unroll
            for (int j = 0; j < 4; ++j)
                op[16 * j] = acc[i][j][r] + bj[j];
        }
    }
}

extern "C" void kernel_launch(void* const* d_in, const int* in_sizes, int n_in,
                              void* d_out, int out_size, void* d_ws, size_t ws_size,
                              hipStream_t stream) {
    const float* A    = (const float*)d_in[0];
    const int*   Q    = (const int*)d_in[1];
    const float* S    = (const float*)d_in[2];
    const int*   Z    = (const int*)d_in[3];
    const float* bias = (const float*)d_in[4];
    float* out = (float*)d_out;

    const int grid = (MDIM / 128) * (NDIM / 128);   // 2752 blocks
    int4_gemm_mfma<<<dim3(grid), dim3(256), 0, stream>>>(A, Q, S, Z, bias, out);
}

// Round 2
// 1145.187 us; speedup vs baseline: 2.0976x; 1.2495x over previous
//
#include <hip/hip_runtime.h>
#include <hip/hip_bf16.h>
#include <stdint.h>

#define MDIM 4096
#define KDIM 4096
#define NDIM 11008

typedef __bf16 bf16x8 __attribute__((ext_vector_type(8)));
typedef float  f32x4  __attribute__((ext_vector_type(4)));

// 128x128 tile, BK=32, 256 threads = 4 waves in 2x2; each wave owns 64x64
// via 4x4 mfma_f32_16x16x32_bf16 fragments. Software-pipelined:
//   - register prefetch of next k-step's A (4x float4) and Q (8x int2)
//   - LDS double-buffered (2 x (8KB A + 8KB B) bf16)
//   - ONE __syncthreads per k-step (loads consumed before the barrier drain)
// Both sA and sB use a 16B-chunk XOR swizzle so ds_read_b128 is ~2-way
// (free) and writes stay b128. Fragment contracts (harness-verified):
//   A operand: lane(fr,fq) holds A[m=16i+fr][k=fq*8+e]
//   B operand: lane(fr,fq) holds B[k=fq*8+e][n=16j+fr]
//   C/D:       col = lane&15, row = (lane>>4)*4 + r
__global__ __launch_bounds__(256) void int4_gemm_mfma(
    const float* __restrict__ A, const int* __restrict__ Q,
    const float* __restrict__ S, const int* __restrict__ Z,
    const float* __restrict__ bias, float* __restrict__ out)
{
    __shared__ __bf16 sA[2][128][32];   // [m][k] bf16, chunk-swizzled
    __shared__ __bf16 sB[2][128][32];   // [n][k] bf16, chunk-swizzled

    // ---- XCD-chunked swizzle, bm fastest: each XCD walks bn (Q) strips ----
    const int nbm = MDIM / 128;                      // 32
    const int nwg = (MDIM / 128) * (NDIM / 128);     // 2752 (divisible by 8)
    const int xcd = blockIdx.x & 7;
    const int wg  = xcd * (nwg >> 3) + (blockIdx.x >> 3);
    const int bm  = wg % nbm;
    const int bn  = wg / nbm;
    const int m0 = bm * 128, n0 = bn * 128;

    const int t    = threadIdx.x;
    const int lane = t & 63;
    const int wave = t >> 6;
    const int wm   = (wave >> 1) * 64;   // wave quadrant (64x64)
    const int wn   = (wave & 1) * 64;
    const int fr   = lane & 15;
    const int fq   = lane >> 4;          // k-octet

    // ---- staging maps ----
    const int arow = t >> 2;                                   // 0..63
    const int acol = ((t & 3) ^ ((arow >> 1) & 3)) * 8;        // swizzled A chunk
    const int bn2    = lane * 2;                               // 0..126
    const int bko    = wave * 8;                               // k rows bko..+7
    const int bchunk = (wave ^ (lane & 3)) * 8;                // swizzled B chunk

    // fragment read chunks (swizzle inverses)
    const int archk = (fq ^ ((fr >> 1) & 3)) * 8;              // A read chunk
    const int brchk = (fq ^ ((fr >> 1) & 3)) * 8;              // B read chunk

    f32x4 acc[4][4];
    #pragma unroll
    for (int i = 0; i < 4; ++i)
        #pragma unroll
        for (int j = 0; j < 4; ++j)
            #pragma unroll
            for (int r = 0; r < 4; ++r)
                acc[i][j][r] = 0.0f;

    // ---- prefetch registers ----
    float4 ra0, ra1, ra2, ra3;
    int2   rq[8];
    float2 sc;
    int2   zp;

    auto LOAD = [&](int kt) {
        const int k0 = kt * 32;
        const float* ap = A + (size_t)(m0 + arow) * KDIM + k0 + (t & 3) * 8;
        ra0 = ((const float4*)ap)[0];
        ra1 = ((const float4*)ap)[1];
        const float* aq = ap + (size_t)64 * KDIM;
        ra2 = ((const float4*)aq)[0];
        ra3 = ((const float4*)aq)[1];
        #pragma unroll
        for (int j = 0; j < 8; ++j)
            rq[j] = *(const int2*)(Q + (size_t)(k0 + bko + j) * NDIM + n0 + bn2);
        if ((kt & 3) == 0) {
            const int g = kt >> 2;
            sc = *(const float2*)(S + (size_t)g * NDIM + n0 + bn2);
            zp = *(const int2*)  (Z + (size_t)g * NDIM + n0 + bn2);
        }
    };

    auto STORE = [&](int buf) {
        bf16x8 v0, v1;
        v0[0] = (__bf16)ra0.x; v0[1] = (__bf16)ra0.y;
        v0[2] = (__bf16)ra0.z; v0[3] = (__bf16)ra0.w;
        v0[4] = (__bf16)ra1.x; v0[5] = (__bf16)ra1.y;
        v0[6] = (__bf16)ra1.z; v0[7] = (__bf16)ra1.w;
        v1[0] = (__bf16)ra2.x; v1[1] = (__bf16)ra2.y;
        v1[2] = (__bf16)ra2.z; v1[3] = (__bf16)ra2.w;
        v1[4] = (__bf16)ra3.x; v1[5] = (__bf16)ra3.y;
        v1[6] = (__bf16)ra3.z; v1[7] = (__bf16)ra3.w;
        *(bf16x8*)&sA[buf][arow][acol]      = v0;
        *(bf16x8*)&sA[buf][arow + 64][acol] = v1;

        const float zs0 = -(float)zp.x * sc.x;
        const float zs1 = -(float)zp.y * sc.y;
        bf16x8 w0, w1;
        #pragma unroll
        for (int j = 0; j < 8; ++j) {
            w0[j] = (__bf16)((float)rq[j].x * sc.x + zs0);
            w1[j] = (__bf16)((float)rq[j].y * sc.y + zs1);
        }
        *(bf16x8*)&sB[buf][bn2][bchunk]     = w0;
        *(bf16x8*)&sB[buf][bn2 + 1][bchunk] = w1;
    };

    // ---- prologue ----
    LOAD(0);
    STORE(0);
    __syncthreads();

    // ---- pipelined main loop: one barrier per k-step ----
    for (int kt = 0; kt < KDIM / 32; ++kt) {
        const int c = kt & 1;

        if (kt < KDIM / 32 - 1) LOAD(kt + 1);   // issue early, consume late

        bf16x8 aF[4], bF[4];
        #pragma unroll
        for (int i = 0; i < 4; ++i)
            aF[i] = *(const bf16x8*)&sA[c][wm + 16 * i + fr][archk];
        #pragma unroll
        for (int j = 0; j < 4; ++j)
            bF[j] = *(const bf16x8*)&sB[c][wn + 16 * j + fr][brchk];

        #pragma unroll
        for (int i = 0; i < 4; ++i)
            #pragma unroll
            for (int j = 0; j < 4; ++j)
                acc[i][j] = __builtin_amdgcn_mfma_f32_16x16x32_bf16(
                                aF[i], bF[j], acc[i][j], 0, 0, 0);

        if (kt < KDIM / 32 - 1) STORE(c ^ 1);   // cvt + LDS write for next step

        __syncthreads();
    }

    // ---- epilogue: C/D col = lane&15, row = (lane>>4)*4 + r ----
    float bj[4];
    #pragma unroll
    for (int j = 0; j < 4; ++j)
        bj[j] = bias[n0 + wn + 16 * j + fr];

    #pragma unroll
    for (int i = 0; i < 4; ++i) {
        #pragma unroll
        for (int r = 0; r < 4; ++r) {
            const int m = m0 + wm + 16 * i + fq * 4 + r;
            float* op = out + (size_t)m * NDIM + n0 + wn + fr;
            #pragma unroll
            for (int j = 0; j < 4; ++j)
                op[16 * j] = acc[i][j][r] + bj[j];
        }
    }
}

extern "C" void kernel_launch(void* const* d_in, const int* in_sizes, int n_in,
                              void* d_out, int out_size, void* d_ws, size_t ws_size,
                              hipStream_t stream) {
    const float* A    = (const float*)d_in[0];
    const int*   Q    = (const int*)d_in[1];
    const float* S    = (const float*)d_in[2];
    const int*   Z    = (const int*)d_in[3];
    const float* bias = (const float*)d_in[4];
    float* out = (float*)d_out;

    const int grid = (MDIM / 128) * (NDIM / 128);   // 2752 blocks
    int4_gemm_mfma<<<dim3(grid), dim3(256), 0, stream>>>(A, Q, S, Z, bias, out);
}

// Round 3
// 1050.204 us; speedup vs baseline: 2.2874x; 1.0904x over previous
//
#include <hip/hip_runtime.h>
#include <hip/hip_bf16.h>
#include <stdint.h>

#define MDIM 4096
#define KDIM 4096
#define NDIM 11008

typedef __bf16 bf16x8 __attribute__((ext_vector_type(8)));
typedef float  f32x4  __attribute__((ext_vector_type(4)));

// 256x256 tile, BK=32, 512 threads = 8 waves (2m x 4n); each wave owns
// 128x64 via 8x4 mfma_f32_16x16x32_bf16 fragments (32 MFMA per k-step).
// Software pipeline: register prefetch of next k-step (A: 4x float4,
// Q: 8x int2) + LDS double-buffer + ONE barrier per k-step.
// LDS layout (both sA and sB): rows of 32 bf16 (4x 16B chunks), stored in
// 2-row 128B windows with slot swizzle:
//   slot(row,c) = ((row&1)*4 + c) ^ ((row>>1)&7)
// -> every b128 read AND write in this kernel spreads 64 lanes uniformly
// over the 8 slots of the 128B bank window (structural minimum).
// Fragment contracts (harness-verified):
//   A operand: lane(fr,fq) holds A[m=16i+fr][k=fq*8+e]
//   B operand: lane(fr,fq) holds B[k=fq*8+e][n=16j+fr]
//   C/D:       col = lane&15, row = (lane>>4)*4 + r
__global__ __launch_bounds__(512) void int4_gemm_mfma(
    const float* __restrict__ A, const int* __restrict__ Q,
    const float* __restrict__ S, const int* __restrict__ Z,
    const float* __restrict__ bias, float* __restrict__ out)
{
    __shared__ __bf16 sA[2][256 * 32];   // 2 x 16KB
    __shared__ __bf16 sB[2][256 * 32];   // 2 x 16KB  ([n][k])

    // byte offset of (row, 16B-chunk c) under the window swizzle
    auto SW = [](int row, int c) -> int {
        return ((row >> 1) << 7) + (((((row & 1) << 2) | c) ^ ((row >> 1) & 7)) << 4);
    };

    // ---- XCD-chunked swizzle, bm fastest ----
    const int nbm = MDIM / 256;                      // 16
    const int nwg = (MDIM / 256) * (NDIM / 256);     // 688 (divisible by 8)
    const int xcd = blockIdx.x & 7;
    const int wg  = xcd * (nwg >> 3) + (blockIdx.x >> 3);
    const int bm  = wg % nbm;
    const int bn  = wg / nbm;
    const int m0 = bm * 256, n0 = bn * 256;

    const int t    = threadIdx.x;
    const int lane = t & 63;
    const int wave = t >> 6;
    const int wm   = (wave >> 2) * 128;  // wave tile: 128m x 64n
    const int wn   = (wave & 3) * 64;
    const int fr   = lane & 15;
    const int fq   = lane >> 4;          // k-octet

    // ---- staging maps ----
    const int arow = t >> 1;             // 0..255, one A row per thread
    const int acb  = (t & 1) * 2;        // A chunk base (k-octets 0,1 or 2,3)
    const int bn2  = (t & 127) * 2;      // 0..254, two B cols per thread
    const int bko  = (t >> 7) * 8;       // k-octet row block
    const int bcc  = t >> 7;             // B chunk = k-octet index (0..3)

    f32x4 acc[8][4];
    #pragma unroll
    for (int i = 0; i < 8; ++i)
        #pragma unroll
        for (int j = 0; j < 4; ++j)
            #pragma unroll
            for (int r = 0; r < 4; ++r)
                acc[i][j][r] = 0.0f;

    // ---- prefetch registers ----
    float4 ra0, ra1, ra2, ra3;
    int2   rq[8];
    float2 sc;
    int2   zp;

    auto LOAD = [&](int kt) {
        const int k0 = kt * 32;
        const float* ap = A + (size_t)(m0 + arow) * KDIM + k0 + (t & 1) * 16;
        ra0 = ((const float4*)ap)[0];
        ra1 = ((const float4*)ap)[1];
        ra2 = ((const float4*)ap)[2];
        ra3 = ((const float4*)ap)[3];
        #pragma unroll
        for (int j = 0; j < 8; ++j)
            rq[j] = *(const int2*)(Q + (size_t)(k0 + bko + j) * NDIM + n0 + bn2);
        if ((kt & 3) == 0) {
            const int g = kt >> 2;
            sc = *(const float2*)(S + (size_t)g * NDIM + n0 + bn2);
            zp = *(const int2*)  (Z + (size_t)g * NDIM + n0 + bn2);
        }
    };

    auto STORE = [&](int buf) {
        bf16x8 v0, v1;
        v0[0] = (__bf16)ra0.x; v0[1] = (__bf16)ra0.y;
        v0[2] = (__bf16)ra0.z; v0[3] = (__bf16)ra0.w;
        v0[4] = (__bf16)ra1.x; v0[5] = (__bf16)ra1.y;
        v0[6] = (__bf16)ra1.z; v0[7] = (__bf16)ra1.w;
        v1[0] = (__bf16)ra2.x; v1[1] = (__bf16)ra2.y;
        v1[2] = (__bf16)ra2.z; v1[3] = (__bf16)ra2.w;
        v1[4] = (__bf16)ra3.x; v1[5] = (__bf16)ra3.y;
        v1[6] = (__bf16)ra3.z; v1[7] = (__bf16)ra3.w;
        *(bf16x8*)((char*)sA[buf] + SW(arow, acb))     = v0;
        *(bf16x8*)((char*)sA[buf] + SW(arow, acb + 1)) = v1;

        const float zs0 = -(float)zp.x * sc.x;
        const float zs1 = -(float)zp.y * sc.y;
        bf16x8 w0, w1;
        #pragma unroll
        for (int j = 0; j < 8; ++j) {
            w0[j] = (__bf16)((float)rq[j].x * sc.x + zs0);
            w1[j] = (__bf16)((float)rq[j].y * sc.y + zs1);
        }
        *(bf16x8*)((char*)sB[buf] + SW(bn2,     bcc)) = w0;
        *(bf16x8*)((char*)sB[buf] + SW(bn2 + 1, bcc)) = w1;
    };

    // ---- prologue ----
    LOAD(0);
    STORE(0);
    __syncthreads();

    // ---- pipelined main loop: one barrier per k-step ----
    for (int kt = 0; kt < KDIM / 32; ++kt) {
        const int c = kt & 1;

        if (kt < KDIM / 32 - 1) LOAD(kt + 1);   // issue early, consume late

        bf16x8 aF[8], bF[4];
        #pragma unroll
        for (int i = 0; i < 8; ++i)
            aF[i] = *(const bf16x8*)((char*)sA[c] + SW(wm + 16 * i + fr, fq));
        #pragma unroll
        for (int j = 0; j < 4; ++j)
            bF[j] = *(const bf16x8*)((char*)sB[c] + SW(wn + 16 * j + fr, fq));

        #pragma unroll
        for (int i = 0; i < 8; ++i)
            #pragma unroll
            for (int j = 0; j < 4; ++j)
                acc[i][j] = __builtin_amdgcn_mfma_f32_16x16x32_bf16(
                                aF[i], bF[j], acc[i][j], 0, 0, 0);

        if (kt < KDIM / 32 - 1) STORE(c ^ 1);   // cvt + dequant + LDS write

        __syncthreads();
    }

    // ---- epilogue: C/D col = lane&15, row = (lane>>4)*4 + r ----
    float bj[4];
    #pragma unroll
    for (int j = 0; j < 4; ++j)
        bj[j] = bias[n0 + wn + 16 * j + fr];

    #pragma unroll
    for (int i = 0; i < 8; ++i) {
        #pragma unroll
        for (int r = 0; r < 4; ++r) {
            const int m = m0 + wm + 16 * i + fq * 4 + r;
            float* op = out + (size_t)m * NDIM + n0 + wn + fr;
            #pragma unroll
            for (int j = 0; j < 4; ++j)
                op[16 * j] = acc[i][j][r] + bj[j];
        }
    }
}

extern "C" void kernel_launch(void* const* d_in, const int* in_sizes, int n_in,
                              void* d_out, int out_size, void* d_ws, size_t ws_size,
                              hipStream_t stream) {
    const float* A    = (const float*)d_in[0];
    const int*   Q    = (const int*)d_in[1];
    const float* S    = (const float*)d_in[2];
    const int*   Z    = (const int*)d_in[3];
    const float* bias = (const float*)d_in[4];
    float* out = (float*)d_out;

    const int grid = (MDIM / 256) * (NDIM / 256);   // 688 blocks
    int4_gemm_mfma<<<dim3(grid), dim3(512), 0, stream>>>(A, Q, S, Z, bias, out);
}

// Round 5
// 895.316 us; speedup vs baseline: 2.6831x; 1.1730x over previous
//
#include <hip/hip_runtime.h>
#include <hip/hip_bf16.h>
#include <stdint.h>

#define MDIM 4096
#define KDIM 4096
#define NDIM 11008
#define NT   (KDIM / 32)   // 128 k-steps

typedef __bf16 bf16x8 __attribute__((ext_vector_type(8)));
typedef float  f32x4  __attribute__((ext_vector_type(4)));

// 256x256 tile, BK=32, 512 threads = 8 waves (2m x 4n); each wave owns
// 128x64 via 8x4 mfma_f32_16x16x32_bf16 fragments (32 MFMA per k-step).
// T4/T14 pipeline: global loads issued at step kt are consumed (dequant +
// LDS write) at step kt+1 -- a full k-step of latency cover from a single
// register bank (consume-then-reissue). Per-step barrier is a raw s_barrier
// preceded by lgkmcnt(0) ONLY: the 12 in-flight global loads cross the
// barrier (no vmcnt(0) drain, unlike __syncthreads). Main loop manually
// 2x-unrolled so LDS buffer indices are compile-time constants.
// T5: setprio(1) around the MFMA cluster.
// LDS (both sA, sB): rows of 32 bf16 (4x 16B chunks) in 2-row 128B windows,
// slot(row,c) = ((row&1)*4 + c) ^ ((row>>1)&7)  -- measured conflict-free
// (round 3: SQ_LDS_BANK_CONFLICT == 0).
// Fragment contracts (harness-verified):
//   A operand: lane(fr,fq) holds A[m=16i+fr][k=fq*8+e]
//   B operand: lane(fr,fq) holds B[k=fq*8+e][n=16j+fr]
//   C/D:       col = lane&15, row = (lane>>4)*4 + r
__global__ __launch_bounds__(512) void int4_gemm_mfma(
    const float* __restrict__ A, const int* __restrict__ Q,
    const float* __restrict__ S, const int* __restrict__ Z,
    const float* __restrict__ bias, float* __restrict__ out)
{
    __shared__ __bf16 sA[2][256 * 32];   // 2 x 16KB
    __shared__ __bf16 sB[2][256 * 32];   // 2 x 16KB  ([n][k])

    auto SW = [](int row, int c) -> int {
        return ((row >> 1) << 7) + (((((row & 1) << 2) | c) ^ ((row >> 1) & 7)) << 4);
    };

    // ---- XCD-chunked swizzle, bm fastest ----
    const int nbm = MDIM / 256;                      // 16
    const int nwg = (MDIM / 256) * (NDIM / 256);     // 688 (divisible by 8)
    const int xcd = blockIdx.x & 7;
    const int wg  = xcd * (nwg >> 3) + (blockIdx.x >> 3);
    const int bm  = wg % nbm;
    const int bn  = wg / nbm;
    const int m0 = bm * 256, n0 = bn * 256;

    const int t    = threadIdx.x;
    const int lane = t & 63;
    const int wave = t >> 6;
    const int wm   = (wave >> 2) * 128;  // wave tile: 128m x 64n
    const int wn   = (wave & 3) * 64;
    const int fr   = lane & 15;
    const int fq   = lane >> 4;          // k-octet

    // ---- staging maps ----
    const int arow = t >> 1;             // 0..255, one A row per thread
    const int acb  = (t & 1) * 2;        // A chunk base (k-octets 0,1 or 2,3)
    const int bn2  = (t & 127) * 2;      // 0..254, two B cols per thread
    const int bko  = (t >> 7) * 8;       // k-octet row block
    const int bcc  = t >> 7;             // B chunk = k-octet index (0..3)

    f32x4 acc[8][4];
    #pragma unroll
    for (int i = 0; i < 8; ++i)
        #pragma unroll
        for (int j = 0; j < 4; ++j)
            #pragma unroll
            for (int r = 0; r < 4; ++r)
                acc[i][j][r] = 0.0f;

    // ---- running global pointers ----
    const float* aP = A + (size_t)(m0 + arow) * KDIM + (t & 1) * 16;
    const int*   qP = Q + (size_t)bko * NDIM + n0 + bn2;

    // ---- prefetch register bank (consumed at kt, reissued at kt) ----
    float4 ra0, ra1, ra2, ra3;
    int2   rq[8];
    float2 sc;
    int2   zp;

    auto LOAD = [&](int kt) {
        ra0 = ((const float4*)aP)[0];
        ra1 = ((const float4*)aP)[1];
        ra2 = ((const float4*)aP)[2];
        ra3 = ((const float4*)aP)[3];
        const int* q = qP;
        #pragma unroll
        for (int j = 0; j < 8; ++j) {
            rq[j] = *(const int2*)q;
            q += NDIM;
        }
        if ((kt & 3) == 0) {            // params for group kt>>2; prior
            const int g = kt >> 2;      // group's last STORE already done
            sc = *(const float2*)(S + (size_t)g * NDIM + n0 + bn2);
            zp = *(const int2*)  (Z + (size_t)g * NDIM + n0 + bn2);
        }
        aP += 32;
        qP += (size_t)32 * NDIM;
    };

    auto STORE = [&](int buf) {
        bf16x8 v0, v1;
        v0[0] = (__bf16)ra0.x; v0[1] = (__bf16)ra0.y;
        v0[2] = (__bf16)ra0.z; v0[3] = (__bf16)ra0.w;
        v0[4] = (__bf16)ra1.x; v0[5] = (__bf16)ra1.y;
        v0[6] = (__bf16)ra1.z; v0[7] = (__bf16)ra1.w;
        v1[0] = (__bf16)ra2.x; v1[1] = (__bf16)ra2.y;
        v1[2] = (__bf16)ra2.z; v1[3] = (__bf16)ra2.w;
        v1[4] = (__bf16)ra3.x; v1[5] = (__bf16)ra3.y;
        v1[6] = (__bf16)ra3.z; v1[7] = (__bf16)ra3.w;
        *(bf16x8*)((char*)sA[buf] + SW(arow, acb))     = v0;
        *(bf16x8*)((char*)sA[buf] + SW(arow, acb + 1)) = v1;

        const float zs0 = -(float)zp.x * sc.x;
        const float zs1 = -(float)zp.y * sc.y;
        bf16x8 w0, w1;
        #pragma unroll
        for (int j = 0; j < 8; ++j) {
            w0[j] = (__bf16)((float)rq[j].x * sc.x + zs0);
            w1[j] = (__bf16)((float)rq[j].y * sc.y + zs1);
        }
        *(bf16x8*)((char*)sB[buf] + SW(bn2,     bcc)) = w0;
        *(bf16x8*)((char*)sB[buf] + SW(bn2 + 1, bcc)) = w1;
    };

    auto FRAGS = [&](int buf, bf16x8 (&aF)[8], bf16x8 (&bF)[4]) {
        #pragma unroll
        for (int i = 0; i < 8; ++i)
            aF[i] = *(const bf16x8*)((char*)sA[buf] + SW(wm + 16 * i + fr, fq));
        #pragma unroll
        for (int j = 0; j < 4; ++j)
            bF[j] = *(const bf16x8*)((char*)sB[buf] + SW(wn + 16 * j + fr, fq));
    };

    auto MFMAS = [&](bf16x8 (&aF)[8], bf16x8 (&bF)[4]) {
        __builtin_amdgcn_s_setprio(1);
        #pragma unroll
        for (int i = 0; i < 8; ++i)
            #pragma unroll
            for (int j = 0; j < 4; ++j)
                acc[i][j] = __builtin_amdgcn_mfma_f32_16x16x32_bf16(
                                aF[i], bF[j], acc[i][j], 0, 0, 0);
        __builtin_amdgcn_s_setprio(0);
    };

    auto BAR = [&]() {   // release own LDS ops, raw barrier; globals fly over
        asm volatile("s_waitcnt lgkmcnt(0)" ::: "memory");
        __builtin_amdgcn_s_barrier();
    };

    // ---- prologue: buf0 = tile0; tile1's loads left IN FLIGHT ----
    LOAD(0);
    STORE(0);                       // compiler inserts exact vmcnt waits
    LOAD(1);
    BAR();

    // ---- main loop, 2x unrolled: one raw barrier per k-step ----
    for (int kt = 0; kt < NT; kt += 2) {
        {   // half A: compute buf0 (tile kt); stage tile kt+1 -> buf1
            bf16x8 aF[8], bF[4];
            FRAGS(0, aF, bF);
            STORE(1);                          // regs = tile kt+1 (issued kt-1)
            if (kt + 2 < NT) LOAD(kt + 2);     // reissue bank for tile kt+2
            MFMAS(aF, bF);
            BAR();
        }
        {   // half B: compute buf1 (tile kt+1); stage tile kt+2 -> buf0
            bf16x8 aF[8], bF[4];
            FRAGS(1, aF, bF);
            if (kt + 2 < NT) STORE(0);         // regs = tile kt+2
            if (kt + 3 < NT) LOAD(kt + 3);
            MFMAS(aF, bF);
            BAR();
        }
    }

    // ---- epilogue: C/D col = lane&15, row = (lane>>4)*4 + r ----
    float bj[4];
    #pragma unroll
    for (int j = 0; j < 4; ++j)
        bj[j] = bias[n0 + wn + 16 * j + fr];

    #pragma unroll
    for (int i = 0; i < 8; ++i) {
        #pragma unroll
        for (int r = 0; r < 4; ++r) {
            const int m = m0 + wm + 16 * i + fq * 4 + r;
            float* op = out + (size_t)m * NDIM + n0 + wn + fr;
            #pragma unroll
            for (int j = 0; j < 4; ++j)
                op[16 * j] = acc[i][j][r] + bj[j];
        }
    }
}

extern "C" void kernel_launch(void* const* d_in, const int* in_sizes, int n_in,
                              void* d_out, int out_size, void* d_ws, size_t ws_size,
                              hipStream_t stream) {
    const float* A    = (const float*)d_in[0];
    const int*   Q    = (const int*)d_in[1];
    const float* S    = (const float*)d_in[2];
    const int*   Z    = (const int*)d_in[3];
    const float* bias = (const float*)d_in[4];
    float* out = (float*)d_out;

    const int grid = (MDIM / 256) * (NDIM / 256);   // 688 blocks
    int4_gemm_mfma<<<dim3(grid), dim3(512), 0, stream>>>(A, Q, S, Z, bias, out);
}